// Round 1
// baseline (219.110 us; speedup 1.0000x reference)
//
#include <hip/hip_runtime.h>
#include <hip/hip_bf16.h>
#include <math.h>

// B=1024, N=500, D=128, H=8, L=2, CLIP=10
constexpr int NKEY = 500;
constexpr int DIM = 128;
constexpr int HEADS = 8;
constexpr int ROWSTRIDE = 256;   // D*L floats per K/V row

__global__ __launch_bounds__(256)
void fused_pomo_attn(const float* __restrict__ query,   // (B,1,128)
                     const float* __restrict__ K_att,   // (B,500,256)
                     const float* __restrict__ V_att,   // (B,500,256)
                     const int*   __restrict__ mask,    // (B,500) int32 0/1
                     const float* __restrict__ W0_w,    // (128,128)
                     const float* __restrict__ W0_b,    // (128,)
                     const float* __restrict__ Wq_w,    // (128,128)
                     const float* __restrict__ Wq_b,    // (128,)
                     float* __restrict__ out)           // (B,500)
{
    const int b = blockIdx.x;
    const int tid = threadIdx.x;
    const int lane32 = tid & 31;   // position within a 32-lane row group
    const int grp = tid >> 5;      // row group 0..7

    __shared__ alignas(16) float s_sc[HEADS][NKEY];  // layer-0 scores/weights
    __shared__ alignas(16) float s_red[8][DIM];      // PV cross-group reduce
    __shared__ alignas(16) float s_out[DIM];         // layer-0 attention output
    __shared__ alignas(16) float s_q1[DIM];          // after W0
    __shared__ alignas(16) float s_qf[DIM];          // after Wq
    __shared__ alignas(16) float s_s1[NKEY];         // layer-1 scores
    __shared__ float s_m[4], s_l[4];

    const size_t brow = (size_t)b * NKEY;

    // ---------- Pass 1: layer-0 scores (read K0: 256 KB) ----------
    // 32 lanes per row, lane c holds dims [4c,4c+4); head = c>>2 (dh=16)
    const float4 q4 = ((const float4*)(query + (size_t)b * DIM))[lane32];
    for (int base = 0; base < NKEY; base += 8) {
        const int n = base + grp;
        float s = 0.f;
        if (n < NKEY) {
            const float4 k4 = ((const float4*)(K_att + (brow + n) * ROWSTRIDE))[lane32];
            s = q4.x*k4.x + q4.y*k4.y + q4.z*k4.z + q4.w*k4.w;
        }
        s += __shfl_xor(s, 1);
        s += __shfl_xor(s, 2);
        if (n < NKEY && (lane32 & 3) == 0) {
            float sc = s * 0.25f;                    // 1/sqrt(16)
            if (mask[brow + n] != 0) sc = -1e9f;
            s_sc[lane32 >> 2][n] = sc;
        }
    }
    __syncthreads();

    // ---------- Pass 2: per-head softmax (group g handles head g) ----------
    {
        float m = -INFINITY;
        for (int n = lane32; n < NKEY; n += 32) m = fmaxf(m, s_sc[grp][n]);
        #pragma unroll
        for (int o = 16; o > 0; o >>= 1) m = fmaxf(m, __shfl_xor(m, o));
        float l = 0.f;
        for (int n = lane32; n < NKEY; n += 32) {
            const float e = __expf(s_sc[grp][n] - m);
            s_sc[grp][n] = e;
            l += e;
        }
        #pragma unroll
        for (int o = 16; o > 0; o >>= 1) l += __shfl_xor(l, o);
        const float inv = 1.f / l;
        for (int n = lane32; n < NKEY; n += 32) s_sc[grp][n] *= inv;
    }
    __syncthreads();

    // ---------- Pass 3: PV (read V0: 256 KB) ----------
    {
        float4 acc = make_float4(0.f, 0.f, 0.f, 0.f);
        const int h = lane32 >> 2;
        for (int base = 0; base < NKEY; base += 8) {
            const int n = base + grp;
            if (n < NKEY) {
                const float4 v4 = ((const float4*)(V_att + (brow + n) * ROWSTRIDE))[lane32];
                const float w = s_sc[h][n];
                acc.x += w * v4.x; acc.y += w * v4.y;
                acc.z += w * v4.z; acc.w += w * v4.w;
            }
        }
        ((float4*)s_red[grp])[lane32] = acc;
    }
    __syncthreads();
    if (tid < DIM) {
        float v = 0.f;
        #pragma unroll
        for (int g = 0; g < 8; g++) v += s_red[g][tid];
        s_out[tid] = v;
    }
    __syncthreads();

    // ---------- Pass 4: q1 = s_out @ W0^T + b (2 threads per output) ----------
    {
        const int i = tid >> 1, half = tid & 1;
        const float4* wrow = (const float4*)(W0_w + (size_t)i * DIM + half * 64);
        float ssum = 0.f;
        #pragma unroll
        for (int k = 0; k < 16; k++) {
            const float4 w4 = wrow[k];
            const float4 o4 = ((const float4*)s_out)[half * 16 + k];
            ssum += w4.x*o4.x + w4.y*o4.y + w4.z*o4.z + w4.w*o4.w;
        }
        ssum += __shfl_xor(ssum, 1);
        if (half == 0) s_q1[i] = ssum + W0_b[i];
    }
    __syncthreads();

    // ---------- Pass 5: qf = s_q1 @ Wq^T + b ----------
    {
        const int i = tid >> 1, half = tid & 1;
        const float4* wrow = (const float4*)(Wq_w + (size_t)i * DIM + half * 64);
        float ssum = 0.f;
        #pragma unroll
        for (int k = 0; k < 16; k++) {
            const float4 w4 = wrow[k];
            const float4 o4 = ((const float4*)s_q1)[half * 16 + k];
            ssum += w4.x*o4.x + w4.y*o4.y + w4.z*o4.z + w4.w*o4.w;
        }
        ssum += __shfl_xor(ssum, 1);
        if (half == 0) s_qf[i] = ssum + Wq_b[i];
    }
    __syncthreads();

    // ---------- Pass 6: layer-1 scores (read K1: 256 KB) ----------
    {
        const float4 qf4 = ((const float4*)s_qf)[lane32];
        for (int base = 0; base < NKEY; base += 8) {
            const int n = base + grp;
            float s = 0.f;
            if (n < NKEY) {
                const float4 k4 = ((const float4*)(K_att + (brow + n) * ROWSTRIDE + DIM))[lane32];
                s = qf4.x*k4.x + qf4.y*k4.y + qf4.z*k4.z + qf4.w*k4.w;
            }
            #pragma unroll
            for (int o = 1; o < 32; o <<= 1) s += __shfl_xor(s, o);
            if (n < NKEY && lane32 == 0) {
                float sc = s * 0.08838834764831845f;   // 1/sqrt(128)
                sc = 10.f * tanhf(sc);
                if (mask[brow + n] != 0) sc = -1e9f;
                s_s1[n] = sc;
            }
        }
    }
    __syncthreads();

    // ---------- Pass 7: block softmax over 500 + write ----------
    {
        const int wid = tid >> 6;
        const int lane = tid & 63;
        float m = -INFINITY;
        for (int n = tid; n < NKEY; n += 256) m = fmaxf(m, s_s1[n]);
        #pragma unroll
        for (int o = 32; o > 0; o >>= 1) m = fmaxf(m, __shfl_xor(m, o));
        if (lane == 0) s_m[wid] = m;
        __syncthreads();
        m = fmaxf(fmaxf(s_m[0], s_m[1]), fmaxf(s_m[2], s_m[3]));
        float l = 0.f;
        for (int n = tid; n < NKEY; n += 256) {
            const float e = __expf(s_s1[n] - m);
            s_s1[n] = e;
            l += e;
        }
        #pragma unroll
        for (int o = 32; o > 0; o >>= 1) l += __shfl_xor(l, o);
        if (lane == 0) s_l[wid] = l;
        __syncthreads();
        l = s_l[0] + s_l[1] + s_l[2] + s_l[3];
        const float inv = 1.f / l;
        float* op = out + brow;
        for (int n = tid; n < NKEY; n += 256) op[n] = s_s1[n] * inv;
    }
}

extern "C" void kernel_launch(void* const* d_in, const int* in_sizes, int n_in,
                              void* d_out, int out_size, void* d_ws, size_t ws_size,
                              hipStream_t stream) {
    const float* query = (const float*)d_in[0];
    const float* K_att = (const float*)d_in[1];
    const float* V_att = (const float*)d_in[2];
    const int*   mask  = (const int*)d_in[3];
    const float* W0_w  = (const float*)d_in[4];
    const float* W0_b  = (const float*)d_in[5];
    const float* Wq_w  = (const float*)d_in[6];
    const float* Wq_b  = (const float*)d_in[7];
    float* out = (float*)d_out;

    const int B = in_sizes[0] / DIM;   // 1024
    fused_pomo_attn<<<B, 256, 0, stream>>>(query, K_att, V_att, mask,
                                           W0_w, W0_b, Wq_w, Wq_b, out);
}

// Round 2
// 122.701 us; speedup vs baseline: 1.7857x; 1.7857x over previous
//
#include <hip/hip_runtime.h>
#include <hip/hip_bf16.h>
#include <math.h>

// B=1024, N=500, D=128, H=8, L=2, CLIP=10
constexpr int NKEY = 500;
constexpr int DIM = 128;
constexpr int HEADS = 8;
constexpr int ROWSTRIDE = 256;   // D*L floats per K/V row

__global__ __launch_bounds__(256)
void fused_pomo_attn(const float* __restrict__ query,   // (B,1,128)
                     const float* __restrict__ K_att,   // (B,500,256)
                     const float* __restrict__ V_att,   // (B,500,256)
                     const int*   __restrict__ mask,    // (B,500) int32 0/1
                     const float* __restrict__ W0_w,    // (128,128)
                     const float* __restrict__ W0_b,    // (128,)
                     const float* __restrict__ Wq_w,    // (128,128)
                     const float* __restrict__ Wq_b,    // (128,)
                     float* __restrict__ out)           // (B,500)
{
    const int b = blockIdx.x;
    const int tid = threadIdx.x;
    const int lane32 = tid & 31;   // position within a 32-lane row group
    const int grp = tid >> 5;      // row group 0..7

    __shared__ alignas(16) float s_sc[HEADS][NKEY];  // layer-0 scores/weights (compacted)
    __shared__ alignas(16) float s_red[8][DIM];      // PV cross-group reduce
    __shared__ alignas(16) float s_out[DIM];         // layer-0 attention output
    __shared__ alignas(16) float s_q1[DIM];          // after W0
    __shared__ alignas(16) float s_qf[DIM];          // after Wq
    __shared__ alignas(16) float s_s1[NKEY];         // layer-1 scores (compacted)
    __shared__ int s_idx[NKEY];                      // compacted unmasked indices
    __shared__ int s_cnt;
    __shared__ float s_m[4], s_l[4];

    const size_t brow = (size_t)b * NKEY;

    // ---------- Pass 0: ordered compaction of unmasked indices (wave 0) ----------
    if (tid < 64) {
        int off = 0;
        for (int base = 0; base < NKEY; base += 64) {
            const int n = base + tid;
            const bool keep = (n < NKEY) && (mask[brow + n] == 0);
            const unsigned long long bal = __ballot(keep);
            const int pre = __popcll(bal & ((1ull << tid) - 1ull));
            if (keep) s_idx[off + pre] = n;
            off += __popcll(bal);
        }
        if (tid == 0) s_cnt = off;
    }
    __syncthreads();
    const int M = s_cnt;   // >= 1 (position 0 never masked)

    // ---------- Pass 1: layer-0 scores over compacted rows (2x unrolled) ----------
    // 32 lanes per row, lane c holds dims [4c,4c+4); head = c>>2 (dh=16)
    const float4 q4 = ((const float4*)(query + (size_t)b * DIM))[lane32];
    for (int base = 0; base < M; base += 16) {
        const int p0 = base + grp;
        const int p1 = base + 8 + grp;
        const bool ok0 = p0 < M, ok1 = p1 < M;
        const int n0 = ok0 ? s_idx[p0] : 0;
        const int n1 = ok1 ? s_idx[p1] : 0;
        float4 k0 = make_float4(0.f,0.f,0.f,0.f), k1 = make_float4(0.f,0.f,0.f,0.f);
        if (ok0) k0 = ((const float4*)(K_att + (brow + n0) * ROWSTRIDE))[lane32];
        if (ok1) k1 = ((const float4*)(K_att + (brow + n1) * ROWSTRIDE))[lane32];
        float s0 = q4.x*k0.x + q4.y*k0.y + q4.z*k0.z + q4.w*k0.w;
        float s1 = q4.x*k1.x + q4.y*k1.y + q4.z*k1.z + q4.w*k1.w;
        s0 += __shfl_xor(s0, 1); s0 += __shfl_xor(s0, 2);
        s1 += __shfl_xor(s1, 1); s1 += __shfl_xor(s1, 2);
        if ((lane32 & 3) == 0) {
            const int h = lane32 >> 2;
            if (ok0) s_sc[h][p0] = s0 * 0.25f;   // 1/sqrt(16)
            if (ok1) s_sc[h][p1] = s1 * 0.25f;
        }
    }
    __syncthreads();

    // ---------- Pass 2: per-head softmax (group g handles head g) ----------
    {
        float m = -INFINITY;
        for (int p = lane32; p < M; p += 32) m = fmaxf(m, s_sc[grp][p]);
        #pragma unroll
        for (int o = 16; o > 0; o >>= 1) m = fmaxf(m, __shfl_xor(m, o));
        float l = 0.f;
        for (int p = lane32; p < M; p += 32) {
            const float e = __expf(s_sc[grp][p] - m);
            s_sc[grp][p] = e;
            l += e;
        }
        #pragma unroll
        for (int o = 16; o > 0; o >>= 1) l += __shfl_xor(l, o);
        const float inv = 1.f / l;
        for (int p = lane32; p < M; p += 32) s_sc[grp][p] *= inv;
    }
    __syncthreads();

    // ---------- Pass 3: PV over compacted rows (2x unrolled) ----------
    {
        float4 acc = make_float4(0.f, 0.f, 0.f, 0.f);
        const int h = lane32 >> 2;
        for (int base = 0; base < M; base += 16) {
            const int p0 = base + grp;
            const int p1 = base + 8 + grp;
            const bool ok0 = p0 < M, ok1 = p1 < M;
            const int n0 = ok0 ? s_idx[p0] : 0;
            const int n1 = ok1 ? s_idx[p1] : 0;
            float4 v0 = make_float4(0.f,0.f,0.f,0.f), v1 = make_float4(0.f,0.f,0.f,0.f);
            if (ok0) v0 = ((const float4*)(V_att + (brow + n0) * ROWSTRIDE))[lane32];
            if (ok1) v1 = ((const float4*)(V_att + (brow + n1) * ROWSTRIDE))[lane32];
            const float w0 = ok0 ? s_sc[h][p0] : 0.f;
            const float w1 = ok1 ? s_sc[h][p1] : 0.f;
            acc.x += w0 * v0.x + w1 * v1.x;
            acc.y += w0 * v0.y + w1 * v1.y;
            acc.z += w0 * v0.z + w1 * v1.z;
            acc.w += w0 * v0.w + w1 * v1.w;
        }
        ((float4*)s_red[grp])[lane32] = acc;
    }
    __syncthreads();
    if (tid < DIM) {
        float v = 0.f;
        #pragma unroll
        for (int g = 0; g < 8; g++) v += s_red[g][tid];
        s_out[tid] = v;
    }
    __syncthreads();

    // ---------- Pass 4: q1 = s_out @ W0^T + b (2 threads per output) ----------
    {
        const int i = tid >> 1, half = tid & 1;
        const float4* wrow = (const float4*)(W0_w + (size_t)i * DIM + half * 64);
        float ssum = 0.f;
        #pragma unroll
        for (int k = 0; k < 16; k++) {
            const float4 w4 = wrow[k];
            const float4 o4 = ((const float4*)s_out)[half * 16 + k];
            ssum += w4.x*o4.x + w4.y*o4.y + w4.z*o4.z + w4.w*o4.w;
        }
        ssum += __shfl_xor(ssum, 1);
        if (half == 0) s_q1[i] = ssum + W0_b[i];
    }
    __syncthreads();

    // ---------- Pass 5: qf = s_q1 @ Wq^T + b ----------
    {
        const int i = tid >> 1, half = tid & 1;
        const float4* wrow = (const float4*)(Wq_w + (size_t)i * DIM + half * 64);
        float ssum = 0.f;
        #pragma unroll
        for (int k = 0; k < 16; k++) {
            const float4 w4 = wrow[k];
            const float4 o4 = ((const float4*)s_q1)[half * 16 + k];
            ssum += w4.x*o4.x + w4.y*o4.y + w4.z*o4.z + w4.w*o4.w;
        }
        ssum += __shfl_xor(ssum, 1);
        if (half == 0) s_qf[i] = ssum + Wq_b[i];
    }
    __syncthreads();

    // ---------- Pass 6: layer-1 scores over compacted rows (2x unrolled) ----------
    {
        const float4 qf4 = ((const float4*)s_qf)[lane32];
        for (int base = 0; base < M; base += 16) {
            const int p0 = base + grp;
            const int p1 = base + 8 + grp;
            const bool ok0 = p0 < M, ok1 = p1 < M;
            const int n0 = ok0 ? s_idx[p0] : 0;
            const int n1 = ok1 ? s_idx[p1] : 0;
            float4 k0 = make_float4(0.f,0.f,0.f,0.f), k1 = make_float4(0.f,0.f,0.f,0.f);
            if (ok0) k0 = ((const float4*)(K_att + (brow + n0) * ROWSTRIDE + DIM))[lane32];
            if (ok1) k1 = ((const float4*)(K_att + (brow + n1) * ROWSTRIDE + DIM))[lane32];
            float s0 = qf4.x*k0.x + qf4.y*k0.y + qf4.z*k0.z + qf4.w*k0.w;
            float s1 = qf4.x*k1.x + qf4.y*k1.y + qf4.z*k1.z + qf4.w*k1.w;
            #pragma unroll
            for (int o = 1; o < 32; o <<= 1) { s0 += __shfl_xor(s0, o); s1 += __shfl_xor(s1, o); }
            if (lane32 == 0) {
                if (ok0) s_s1[p0] = 10.f * tanhf(s0 * 0.08838834764831845f);
                if (ok1) s_s1[p1] = 10.f * tanhf(s1 * 0.08838834764831845f);
            }
        }
    }
    // zero the full output row (masked positions are exactly 0)
    for (int n = tid; n < NKEY; n += 256) out[brow + n] = 0.f;
    __syncthreads();

    // ---------- Pass 7: block softmax over M + scatter write ----------
    {
        const int wid = tid >> 6;
        const int lane = tid & 63;
        float m = -INFINITY;
        for (int p = tid; p < M; p += 256) m = fmaxf(m, s_s1[p]);
        #pragma unroll
        for (int o = 32; o > 0; o >>= 1) m = fmaxf(m, __shfl_xor(m, o));
        if (lane == 0) s_m[wid] = m;
        __syncthreads();
        m = fmaxf(fmaxf(s_m[0], s_m[1]), fmaxf(s_m[2], s_m[3]));
        float l = 0.f;
        for (int p = tid; p < M; p += 256) {
            const float e = __expf(s_s1[p] - m);
            s_s1[p] = e;
            l += e;
        }
        #pragma unroll
        for (int o = 32; o > 0; o >>= 1) l += __shfl_xor(l, o);
        if (lane == 0) s_l[wid] = l;
        __syncthreads();
        l = s_l[0] + s_l[1] + s_l[2] + s_l[3];
        const float inv = 1.f / l;
        for (int p = tid; p < M; p += 256) out[brow + s_idx[p]] = s_s1[p] * inv;
    }
}

extern "C" void kernel_launch(void* const* d_in, const int* in_sizes, int n_in,
                              void* d_out, int out_size, void* d_ws, size_t ws_size,
                              hipStream_t stream) {
    const float* query = (const float*)d_in[0];
    const float* K_att = (const float*)d_in[1];
    const float* V_att = (const float*)d_in[2];
    const int*   mask  = (const int*)d_in[3];
    const float* W0_w  = (const float*)d_in[4];
    const float* W0_b  = (const float*)d_in[5];
    const float* Wq_w  = (const float*)d_in[6];
    const float* Wq_b  = (const float*)d_in[7];
    float* out = (float*)d_out;

    const int B = in_sizes[0] / DIM;   // 1024
    fused_pomo_attn<<<B, 256, 0, stream>>>(query, K_att, V_att, mask,
                                           W0_w, W0_b, Wq_w, Wq_b, out);
}

// Round 3
// 121.176 us; speedup vs baseline: 1.8082x; 1.0126x over previous
//
#include <hip/hip_runtime.h>
#include <hip/hip_bf16.h>
#include <math.h>

// B=1024, N=500, D=128, H=8, L=2, CLIP=10
constexpr int NKEY = 500;
constexpr int DIM = 128;
constexpr int ROWSTRIDE = 256;   // D*L floats per K/V row

__global__ __launch_bounds__(256)
void fused_pomo_attn(const float* __restrict__ query,   // (B,1,128)
                     const float* __restrict__ K_att,   // (B,500,256)
                     const float* __restrict__ V_att,   // (B,500,256)
                     const int*   __restrict__ mask,    // (B,500) int32 0/1
                     const float* __restrict__ W0_w,    // (128,128)
                     const float* __restrict__ W0_b,    // (128,)
                     const float* __restrict__ Wq_w,    // (128,128)
                     const float* __restrict__ Wq_b,    // (128,)
                     float* __restrict__ out)           // (B,500)
{
    const int b = blockIdx.x;
    const int tid = threadIdx.x;
    const int lane32 = tid & 31;   // position within a 32-lane row group
    const int grp = tid >> 5;      // row group 0..7

    __shared__ alignas(16) float s_red[8][DIM];      // per-group PV partial acc
    __shared__ float s_m8[8][32];                    // per-group running max (per lane)
    __shared__ float s_l8[8][32];                    // per-group running sum
    __shared__ alignas(16) float s_out[DIM];         // layer-0 attention output
    __shared__ alignas(16) float s_q1[DIM];          // after W0
    __shared__ alignas(16) float s_qf[DIM];          // after Wq
    __shared__ alignas(16) float s_s1[NKEY];         // layer-1 scores (compacted)
    __shared__ int s_idx[NKEY];                      // compacted unmasked indices
    __shared__ int s_cnt;
    __shared__ float s_m[4], s_l[4];

    const size_t brow = (size_t)b * NKEY;

    // ---------- Pass 0: ordered compaction of unmasked indices (wave 0) ----------
    if (tid < 64) {
        int off = 0;
        for (int base = 0; base < NKEY; base += 64) {
            const int n = base + tid;
            const bool keep = (n < NKEY) && (mask[brow + n] == 0);
            const unsigned long long bal = __ballot(keep);
            const int pre = __popcll(bal & ((1ull << tid) - 1ull));
            if (keep) s_idx[off + pre] = n;
            off += __popcll(bal);
        }
        if (tid == 0) s_cnt = off;
    }
    __syncthreads();
    const int M = s_cnt;   // >= 1 (position 0 never masked)

    // ---------- Pass 1 (flash-merged): layer-0 scores + online softmax + PV ----------
    // 32 lanes per row, lane c holds dims [4c,4c+4); head = c>>2 (dh=16)
    {
        const float4 q4 = ((const float4*)(query + (size_t)b * DIM))[lane32];
        float m = -1e30f, l = 0.f;
        float4 acc = make_float4(0.f, 0.f, 0.f, 0.f);
        for (int base = 0; base < M; base += 16) {
            const int p0 = base + grp;
            const int p1 = base + 8 + grp;
            const bool ok0 = p0 < M, ok1 = p1 < M;
            const int n0 = ok0 ? s_idx[p0] : 0;
            const int n1 = ok1 ? s_idx[p1] : 0;
            // issue all 4 row loads (K and V for both rows) before any reduce
            const float4 k0 = ((const float4*)(K_att + (brow + n0) * ROWSTRIDE))[lane32];
            const float4 k1 = ((const float4*)(K_att + (brow + n1) * ROWSTRIDE))[lane32];
            const float4 v0 = ((const float4*)(V_att + (brow + n0) * ROWSTRIDE))[lane32];
            const float4 v1 = ((const float4*)(V_att + (brow + n1) * ROWSTRIDE))[lane32];
            float s0 = q4.x*k0.x + q4.y*k0.y + q4.z*k0.z + q4.w*k0.w;
            float s1 = q4.x*k1.x + q4.y*k1.y + q4.z*k1.z + q4.w*k1.w;
            s0 += __shfl_xor(s0, 1); s0 += __shfl_xor(s0, 2);
            s1 += __shfl_xor(s1, 1); s1 += __shfl_xor(s1, 2);
            s0 = ok0 ? s0 * 0.25f : -1e30f;     // 1/sqrt(16)
            s1 = ok1 ? s1 * 0.25f : -1e30f;
            const float m2 = fmaxf(m, fmaxf(s0, s1));
            const float f  = __expf(m - m2);
            const float w0 = ok0 ? __expf(s0 - m2) : 0.f;
            const float w1 = ok1 ? __expf(s1 - m2) : 0.f;
            l = l * f + w0 + w1;
            acc.x = acc.x * f + w0 * v0.x + w1 * v1.x;
            acc.y = acc.y * f + w0 * v0.y + w1 * v1.y;
            acc.z = acc.z * f + w0 * v0.z + w1 * v1.z;
            acc.w = acc.w * f + w0 * v0.w + w1 * v1.w;
            m = m2;
        }
        ((float4*)s_red[grp])[lane32] = acc;
        s_m8[grp][lane32] = m;
        s_l8[grp][lane32] = l;
    }
    __syncthreads();
    // merge the 8 per-group online-softmax partials (head of dim d is d>>4; quad lane is d>>2)
    if (tid < DIM) {
        const int ql = tid >> 2;
        float M_ = -1e30f;
        #pragma unroll
        for (int g = 0; g < 8; g++) M_ = fmaxf(M_, s_m8[g][ql]);
        float L = 0.f, o = 0.f;
        #pragma unroll
        for (int g = 0; g < 8; g++) {
            const float f = __expf(s_m8[g][ql] - M_);
            L += s_l8[g][ql] * f;
            o += s_red[g][tid] * f;
        }
        s_out[tid] = o / L;
    }
    __syncthreads();

    // ---------- Pass 4: q1 = s_out @ W0^T + b (2 threads per output) ----------
    {
        const int i = tid >> 1, half = tid & 1;
        const float4* wrow = (const float4*)(W0_w + (size_t)i * DIM + half * 64);
        float ssum = 0.f;
        #pragma unroll
        for (int k = 0; k < 16; k++) {
            const float4 w4 = wrow[k];
            const float4 o4 = ((const float4*)s_out)[half * 16 + k];
            ssum += w4.x*o4.x + w4.y*o4.y + w4.z*o4.z + w4.w*o4.w;
        }
        ssum += __shfl_xor(ssum, 1);
        if (half == 0) s_q1[i] = ssum + W0_b[i];
    }
    __syncthreads();

    // ---------- Pass 5: qf = s_q1 @ Wq^T + b ----------
    {
        const int i = tid >> 1, half = tid & 1;
        const float4* wrow = (const float4*)(Wq_w + (size_t)i * DIM + half * 64);
        float ssum = 0.f;
        #pragma unroll
        for (int k = 0; k < 16; k++) {
            const float4 w4 = wrow[k];
            const float4 o4 = ((const float4*)s_q1)[half * 16 + k];
            ssum += w4.x*o4.x + w4.y*o4.y + w4.z*o4.z + w4.w*o4.w;
        }
        ssum += __shfl_xor(ssum, 1);
        if (half == 0) s_qf[i] = ssum + Wq_b[i];
    }
    __syncthreads();

    // ---------- Pass 6: layer-1 scores over compacted rows (4x unrolled) ----------
    {
        const float4 qf4 = ((const float4*)s_qf)[lane32];
        for (int base = 0; base < M; base += 32) {
            const int p0 = base + grp;
            const int p1 = base + 8  + grp;
            const int p2 = base + 16 + grp;
            const int p3 = base + 24 + grp;
            const bool ok0 = p0 < M, ok1 = p1 < M, ok2 = p2 < M, ok3 = p3 < M;
            const int n0 = ok0 ? s_idx[p0] : 0;
            const int n1 = ok1 ? s_idx[p1] : 0;
            const int n2 = ok2 ? s_idx[p2] : 0;
            const int n3 = ok3 ? s_idx[p3] : 0;
            const float4 k0 = ((const float4*)(K_att + (brow + n0) * ROWSTRIDE + DIM))[lane32];
            const float4 k1 = ((const float4*)(K_att + (brow + n1) * ROWSTRIDE + DIM))[lane32];
            const float4 k2 = ((const float4*)(K_att + (brow + n2) * ROWSTRIDE + DIM))[lane32];
            const float4 k3 = ((const float4*)(K_att + (brow + n3) * ROWSTRIDE + DIM))[lane32];
            float s0 = qf4.x*k0.x + qf4.y*k0.y + qf4.z*k0.z + qf4.w*k0.w;
            float s1 = qf4.x*k1.x + qf4.y*k1.y + qf4.z*k1.z + qf4.w*k1.w;
            float s2 = qf4.x*k2.x + qf4.y*k2.y + qf4.z*k2.z + qf4.w*k2.w;
            float s3 = qf4.x*k3.x + qf4.y*k3.y + qf4.z*k3.z + qf4.w*k3.w;
            #pragma unroll
            for (int o = 1; o < 32; o <<= 1) {
                s0 += __shfl_xor(s0, o); s1 += __shfl_xor(s1, o);
                s2 += __shfl_xor(s2, o); s3 += __shfl_xor(s3, o);
            }
            if (lane32 == 0) {
                if (ok0) s_s1[p0] = 10.f * tanhf(s0 * 0.08838834764831845f);
                if (ok1) s_s1[p1] = 10.f * tanhf(s1 * 0.08838834764831845f);
                if (ok2) s_s1[p2] = 10.f * tanhf(s2 * 0.08838834764831845f);
                if (ok3) s_s1[p3] = 10.f * tanhf(s3 * 0.08838834764831845f);
            }
        }
    }
    // zero the full output row (masked positions are exactly 0)
    for (int n = tid; n < NKEY; n += 256) out[brow + n] = 0.f;
    __syncthreads();

    // ---------- Pass 7: block softmax over M + scatter write ----------
    {
        const int wid = tid >> 6;
        const int lane = tid & 63;
        float m = -INFINITY;
        for (int p = tid; p < M; p += 256) m = fmaxf(m, s_s1[p]);
        #pragma unroll
        for (int o = 32; o > 0; o >>= 1) m = fmaxf(m, __shfl_xor(m, o));
        if (lane == 0) s_m[wid] = m;
        __syncthreads();
        m = fmaxf(fmaxf(s_m[0], s_m[1]), fmaxf(s_m[2], s_m[3]));
        float l = 0.f;
        for (int p = tid; p < M; p += 256) {
            const float e = __expf(s_s1[p] - m);
            s_s1[p] = e;
            l += e;
        }
        #pragma unroll
        for (int o = 32; o > 0; o >>= 1) l += __shfl_xor(l, o);
        if (lane == 0) s_l[wid] = l;
        __syncthreads();
        l = s_l[0] + s_l[1] + s_l[2] + s_l[3];
        const float inv = 1.f / l;
        for (int p = tid; p < M; p += 256) out[brow + s_idx[p]] = s_s1[p] * inv;
    }
}

extern "C" void kernel_launch(void* const* d_in, const int* in_sizes, int n_in,
                              void* d_out, int out_size, void* d_ws, size_t ws_size,
                              hipStream_t stream) {
    const float* query = (const float*)d_in[0];
    const float* K_att = (const float*)d_in[1];
    const float* V_att = (const float*)d_in[2];
    const int*   mask  = (const int*)d_in[3];
    const float* W0_w  = (const float*)d_in[4];
    const float* W0_b  = (const float*)d_in[5];
    const float* Wq_w  = (const float*)d_in[6];
    const float* Wq_b  = (const float*)d_in[7];
    float* out = (float*)d_out;

    const int B = in_sizes[0] / DIM;   // 1024
    fused_pomo_attn<<<B, 256, 0, stream>>>(query, K_att, V_att, mask,
                                           W0_w, W0_b, Wq_w, Wq_b, out);
}

// Round 4
// 104.073 us; speedup vs baseline: 2.1054x; 1.1643x over previous
//
#include <hip/hip_runtime.h>
#include <hip/hip_bf16.h>
#include <math.h>

// B=1024, N=500, D=128, H=8, L=2, CLIP=10
constexpr int NKEY = 500;
constexpr int DIM = 128;
constexpr int ROWSTRIDE = 256;   // D*L floats per K/V row

typedef __attribute__((ext_vector_type(4))) float f32x4;

__device__ __forceinline__ f32x4 nt_load4(const float* p) {
    return __builtin_nontemporal_load((const f32x4*)p);
}

__global__ __launch_bounds__(256, 4)
void fused_pomo_attn(const float* __restrict__ query,   // (B,1,128)
                     const float* __restrict__ K_att,   // (B,500,256)
                     const float* __restrict__ V_att,   // (B,500,256)
                     const int*   __restrict__ mask,    // (B,500) int32 0/1
                     const float* __restrict__ W0_w,    // (128,128)
                     const float* __restrict__ W0_b,    // (128,)
                     const float* __restrict__ Wq_w,    // (128,128)
                     const float* __restrict__ Wq_b,    // (128,)
                     float* __restrict__ out)           // (B,500)
{
    const int b = blockIdx.x;
    const int tid = threadIdx.x;
    const int lane32 = tid & 31;   // position within a 32-lane row group
    const int grp = tid >> 5;      // row group 0..7

    __shared__ alignas(16) float s_red[8][DIM];      // per-group PV partial acc
    __shared__ float s_m8[8][32];                    // per-group running max (per lane)
    __shared__ float s_l8[8][32];                    // per-group running sum
    __shared__ alignas(16) float s_out[DIM];         // layer-0 attention output
    __shared__ alignas(16) float s_q1[DIM];          // after W0
    __shared__ alignas(16) float s_qf[DIM];          // after Wq
    __shared__ alignas(16) float s_s1[NKEY];         // layer-1 scores (compacted)
    __shared__ int s_idx[NKEY];                      // compacted unmasked indices
    __shared__ int s_cnt;
    __shared__ float s_m[4], s_l[4];

    const size_t brow = (size_t)b * NKEY;

    // ---------- Pass 0: ordered compaction of unmasked indices (wave 0) ----------
    if (tid < 64) {
        int off = 0;
        for (int base = 0; base < NKEY; base += 64) {
            const int n = base + tid;
            const bool keep = (n < NKEY) && (mask[brow + n] == 0);
            const unsigned long long bal = __ballot(keep);
            const int pre = __popcll(bal & ((1ull << tid) - 1ull));
            if (keep) s_idx[off + pre] = n;
            off += __popcll(bal);
        }
        if (tid == 0) s_cnt = off;
    }
    __syncthreads();
    const int M = s_cnt;   // >= 1 (position 0 never masked)
    const int Mm1 = M - 1;

    // ---------- Pass 1 (flash-merged, 4x unrolled): layer-0 scores + online softmax + PV ----------
    // 32 lanes per row, lane c holds dims [4c,4c+4); head = c>>2 (dh=16)
    {
        const f32x4 q4 = ((const f32x4*)(query + (size_t)b * DIM))[lane32];
        const float* Kb = K_att + brow * ROWSTRIDE + lane32 * 4;
        const float* Vb = V_att + brow * ROWSTRIDE + lane32 * 4;
        float m = -1e30f, l = 0.f;
        f32x4 acc; acc[0]=0.f; acc[1]=0.f; acc[2]=0.f; acc[3]=0.f;
        for (int base = 0; base < M; base += 32) {
            const int p0 = base + grp, p1 = p0 + 8, p2 = p0 + 16, p3 = p0 + 24;
            const bool ok0 = p0 < M, ok1 = p1 < M, ok2 = p2 < M, ok3 = p3 < M;
            const int n0 = s_idx[ok0 ? p0 : Mm1];
            const int n1 = s_idx[ok1 ? p1 : Mm1];
            const int n2 = s_idx[ok2 ? p2 : Mm1];
            const int n3 = s_idx[ok3 ? p3 : Mm1];
            // issue all 8 row loads before any reduce
            const f32x4 k0 = nt_load4(Kb + (size_t)n0 * ROWSTRIDE);
            const f32x4 k1 = nt_load4(Kb + (size_t)n1 * ROWSTRIDE);
            const f32x4 k2 = nt_load4(Kb + (size_t)n2 * ROWSTRIDE);
            const f32x4 k3 = nt_load4(Kb + (size_t)n3 * ROWSTRIDE);
            const f32x4 v0 = nt_load4(Vb + (size_t)n0 * ROWSTRIDE);
            const f32x4 v1 = nt_load4(Vb + (size_t)n1 * ROWSTRIDE);
            const f32x4 v2 = nt_load4(Vb + (size_t)n2 * ROWSTRIDE);
            const f32x4 v3 = nt_load4(Vb + (size_t)n3 * ROWSTRIDE);
            float s0 = q4[0]*k0[0] + q4[1]*k0[1] + q4[2]*k0[2] + q4[3]*k0[3];
            float s1 = q4[0]*k1[0] + q4[1]*k1[1] + q4[2]*k1[2] + q4[3]*k1[3];
            float s2 = q4[0]*k2[0] + q4[1]*k2[1] + q4[2]*k2[2] + q4[3]*k2[3];
            float s3 = q4[0]*k3[0] + q4[1]*k3[1] + q4[2]*k3[2] + q4[3]*k3[3];
            s0 += __shfl_xor(s0, 1); s0 += __shfl_xor(s0, 2);
            s1 += __shfl_xor(s1, 1); s1 += __shfl_xor(s1, 2);
            s2 += __shfl_xor(s2, 1); s2 += __shfl_xor(s2, 2);
            s3 += __shfl_xor(s3, 1); s3 += __shfl_xor(s3, 2);
            s0 = ok0 ? s0 * 0.25f : -1e30f;     // 1/sqrt(16)
            s1 = ok1 ? s1 * 0.25f : -1e30f;
            s2 = ok2 ? s2 * 0.25f : -1e30f;
            s3 = ok3 ? s3 * 0.25f : -1e30f;
            const float m2 = fmaxf(fmaxf(fmaxf(s0, s1), fmaxf(s2, s3)), m);
            const float f  = __expf(m - m2);
            const float w0 = ok0 ? __expf(s0 - m2) : 0.f;
            const float w1 = ok1 ? __expf(s1 - m2) : 0.f;
            const float w2 = ok2 ? __expf(s2 - m2) : 0.f;
            const float w3 = ok3 ? __expf(s3 - m2) : 0.f;
            l = l * f + w0 + w1 + w2 + w3;
            acc[0] = acc[0]*f + w0*v0[0] + w1*v1[0] + w2*v2[0] + w3*v3[0];
            acc[1] = acc[1]*f + w0*v0[1] + w1*v1[1] + w2*v2[1] + w3*v3[1];
            acc[2] = acc[2]*f + w0*v0[2] + w1*v1[2] + w2*v2[2] + w3*v3[2];
            acc[3] = acc[3]*f + w0*v0[3] + w1*v1[3] + w2*v2[3] + w3*v3[3];
            m = m2;
        }
        ((f32x4*)s_red[grp])[lane32] = acc;
        s_m8[grp][lane32] = m;
        s_l8[grp][lane32] = l;
    }
    __syncthreads();
    // merge the 8 per-group online-softmax partials (dim d held by quad-lane d>>2)
    if (tid < DIM) {
        const int ql = tid >> 2;
        float M_ = -1e30f;
        #pragma unroll
        for (int g = 0; g < 8; g++) M_ = fmaxf(M_, s_m8[g][ql]);
        float L = 0.f, o = 0.f;
        #pragma unroll
        for (int g = 0; g < 8; g++) {
            const float f = __expf(s_m8[g][ql] - M_);
            L += s_l8[g][ql] * f;
            o += s_red[g][tid] * f;
        }
        s_out[tid] = o / L;
    }
    __syncthreads();

    // ---------- Pass 4: q1 = s_out @ W0^T + b (2 threads per output) ----------
    {
        const int i = tid >> 1, half = tid & 1;
        const float4* wrow = (const float4*)(W0_w + (size_t)i * DIM + half * 64);
        float ssum = 0.f;
        #pragma unroll
        for (int k = 0; k < 16; k++) {
            const float4 w4 = wrow[k];
            const float4 o4 = ((const float4*)s_out)[half * 16 + k];
            ssum += w4.x*o4.x + w4.y*o4.y + w4.z*o4.z + w4.w*o4.w;
        }
        ssum += __shfl_xor(ssum, 1);
        if (half == 0) s_q1[i] = ssum + W0_b[i];
    }
    __syncthreads();

    // ---------- Pass 5: qf = s_q1 @ Wq^T + b ----------
    {
        const int i = tid >> 1, half = tid & 1;
        const float4* wrow = (const float4*)(Wq_w + (size_t)i * DIM + half * 64);
        float ssum = 0.f;
        #pragma unroll
        for (int k = 0; k < 16; k++) {
            const float4 w4 = wrow[k];
            const float4 o4 = ((const float4*)s_q1)[half * 16 + k];
            ssum += w4.x*o4.x + w4.y*o4.y + w4.z*o4.z + w4.w*o4.w;
        }
        ssum += __shfl_xor(ssum, 1);
        if (half == 0) s_qf[i] = ssum + Wq_b[i];
    }
    __syncthreads();

    // ---------- Pass 6: layer-1 scores over compacted rows (8x unrolled) ----------
    {
        const f32x4 qf4 = ((const f32x4*)s_qf)[lane32];
        const float* K1b = K_att + brow * ROWSTRIDE + DIM + lane32 * 4;
        for (int base = 0; base < M; base += 64) {
            int   p[8]; bool ok[8]; int n[8];
            #pragma unroll
            for (int j = 0; j < 8; j++) {
                p[j] = base + 8*j + grp;
                ok[j] = p[j] < M;
                n[j] = s_idx[ok[j] ? p[j] : Mm1];
            }
            f32x4 k[8];
            #pragma unroll
            for (int j = 0; j < 8; j++) k[j] = nt_load4(K1b + (size_t)n[j] * ROWSTRIDE);
            float s[8];
            #pragma unroll
            for (int j = 0; j < 8; j++)
                s[j] = qf4[0]*k[j][0] + qf4[1]*k[j][1] + qf4[2]*k[j][2] + qf4[3]*k[j][3];
            #pragma unroll
            for (int o = 1; o < 32; o <<= 1) {
                #pragma unroll
                for (int j = 0; j < 8; j++) s[j] += __shfl_xor(s[j], o);
            }
            if (lane32 == 0) {
                #pragma unroll
                for (int j = 0; j < 8; j++)
                    if (ok[j]) s_s1[p[j]] = 10.f * tanhf(s[j] * 0.08838834764831845f);
            }
        }
    }
    // zero the full output row (masked positions are exactly 0)
    for (int n = tid; n < NKEY; n += 256) out[brow + n] = 0.f;
    __syncthreads();

    // ---------- Pass 7: block softmax over M + scatter write ----------
    {
        const int wid = tid >> 6;
        const int lane = tid & 63;
        float m = -INFINITY;
        for (int p = tid; p < M; p += 256) m = fmaxf(m, s_s1[p]);
        #pragma unroll
        for (int o = 32; o > 0; o >>= 1) m = fmaxf(m, __shfl_xor(m, o));
        if (lane == 0) s_m[wid] = m;
        __syncthreads();
        m = fmaxf(fmaxf(s_m[0], s_m[1]), fmaxf(s_m[2], s_m[3]));
        float l = 0.f;
        for (int p = tid; p < M; p += 256) {
            const float e = __expf(s_s1[p] - m);
            s_s1[p] = e;
            l += e;
        }
        #pragma unroll
        for (int o = 32; o > 0; o >>= 1) l += __shfl_xor(l, o);
        if (lane == 0) s_l[wid] = l;
        __syncthreads();
        l = s_l[0] + s_l[1] + s_l[2] + s_l[3];
        const float inv = 1.f / l;
        for (int p = tid; p < M; p += 256) out[brow + s_idx[p]] = s_s1[p] * inv;
    }
}

extern "C" void kernel_launch(void* const* d_in, const int* in_sizes, int n_in,
                              void* d_out, int out_size, void* d_ws, size_t ws_size,
                              hipStream_t stream) {
    const float* query = (const float*)d_in[0];
    const float* K_att = (const float*)d_in[1];
    const float* V_att = (const float*)d_in[2];
    const int*   mask  = (const int*)d_in[3];
    const float* W0_w  = (const float*)d_in[4];
    const float* W0_b  = (const float*)d_in[5];
    const float* Wq_w  = (const float*)d_in[6];
    const float* Wq_b  = (const float*)d_in[7];
    float* out = (float*)d_out;

    const int B = in_sizes[0] / DIM;   // 1024
    fused_pomo_attn<<<B, 256, 0, stream>>>(query, K_att, V_att, mask,
                                           W0_w, W0_b, Wq_w, Wq_b, out);
}